// Round 1
// baseline (196.521 us; speedup 1.0000x reference)
//
#include <hip/hip_runtime.h>
#include <hip/hip_bf16.h>

#define BB 4
#define NN 40960
#define KK 16
#define DOUT 16
#define BN_EPS 1e-5f

// One thread per (b, n, k-quad). kq lives in the low 2 bits of the thread id,
// so for each output channel o, consecutive lanes write consecutive float4s:
// out[((b*16+o)*N + n)*16 + 4*kq]  -> lane stride 16 B, fully coalesced 1 KiB
// per wave store.
__global__ __launch_bounds__(256) void Block_72464688218281_kernel(
    const float* __restrict__ xyz,      // [B, N, 3]
    const int*   __restrict__ nidx,     // [B, N, K] (int32)
    const float* __restrict__ W,        // [DOUT, 10]
    const float* __restrict__ gamma,    // [DOUT]
    const float* __restrict__ beta,     // [DOUT]
    const float* __restrict__ rmean,    // [DOUT]
    const float* __restrict__ rvar,     // [DOUT]
    float* __restrict__ out)            // [B, DOUT, N, K]
{
    int t = blockIdx.x * blockDim.x + threadIdx.x;
    if (t >= BB * NN * (KK / 4)) return;

    const int kq = t & 3;          // which quad of K
    const int bn = t >> 2;         // b*N + n
    const int b  = bn / NN;
    const int n  = bn - b * NN;

    // center point
    const float* cp = xyz + (size_t)bn * 3;
    const float cx = cp[0], cy = cp[1], cz = cp[2];

    // 4 neighbor indices, 16B-aligned vector load
    const int4 i4 = *(const int4*)(nidx + (size_t)bn * KK + kq * 4);
    int ids[4] = { i4.x, i4.y, i4.z, i4.w };

    const float* xb = xyz + (size_t)b * NN * 3;

    float nx[4], ny[4], nz[4], rx[4], ry[4], rz[4], dd[4];
#pragma unroll
    for (int j = 0; j < 4; ++j) {
        const float* p = xb + (size_t)ids[j] * 3;
        const float ax = p[0], ay = p[1], az = p[2];
        nx[j] = ax; ny[j] = ay; nz[j] = az;
        const float dx = cx - ax, dy = cy - ay, dz = cz - az;
        rx[j] = dx; ry[j] = dy; rz[j] = dz;
        dd[j] = sqrtf(dx * dx + dy * dy + dz * dz);
    }

    const size_t obase = (size_t)b * DOUT * NN * KK + (size_t)n * KK + kq * 4;

#pragma unroll
    for (int o = 0; o < DOUT; ++o) {
        const float w0 = W[o * 10 + 0], w1 = W[o * 10 + 1], w2 = W[o * 10 + 2];
        const float w3 = W[o * 10 + 3], w4 = W[o * 10 + 4], w5 = W[o * 10 + 5];
        const float w6 = W[o * 10 + 6], w7 = W[o * 10 + 7], w8 = W[o * 10 + 8];
        const float w9 = W[o * 10 + 9];
        const float istd = rsqrtf(rvar[o] + BN_EPS);
        const float sc   = gamma[o] * istd;
        const float sh   = beta[o] - gamma[o] * rmean[o] * istd;

        // center contribution is k-independent
        const float ycen = w4 * cx + w5 * cy + w6 * cz;

        float4 r;
        float* rr = (float*)&r;
#pragma unroll
        for (int j = 0; j < 4; ++j) {
            float y = ycen
                    + w0 * dd[j]
                    + w1 * rx[j] + w2 * ry[j] + w3 * rz[j]
                    + w7 * nx[j] + w8 * ny[j] + w9 * nz[j];
            rr[j] = fmaxf(y * sc + sh, 0.0f);
        }
        *(float4*)(out + obase + (size_t)o * NN * KK) = r;
    }
}

extern "C" void kernel_launch(void* const* d_in, const int* in_sizes, int n_in,
                              void* d_out, int out_size, void* d_ws, size_t ws_size,
                              hipStream_t stream) {
    const float* xyz   = (const float*)d_in[0];
    // d_in[1] = feature, unused by the reference
    const int*   nidx  = (const int*)d_in[2];
    const float* W     = (const float*)d_in[3];
    const float* gamma = (const float*)d_in[4];
    const float* beta  = (const float*)d_in[5];
    const float* rmean = (const float*)d_in[6];
    const float* rvar  = (const float*)d_in[7];
    float* out = (float*)d_out;

    const int total  = BB * NN * (KK / 4);     // 655,360 threads
    const int block  = 256;
    const int grid   = (total + block - 1) / block;  // 2560 blocks
    Block_72464688218281_kernel<<<grid, block, 0, stream>>>(
        xyz, nidx, W, gamma, beta, rmean, rvar, out);
}